// Round 8
// baseline (121880.823 us; speedup 1.0000x reference)
//
#include <hip/hip_runtime.h>
#include <hip/hip_bf16.h>

// Adaptive binary arithmetic encoder, bit-exact port of the JAX reference.
// Phase 1 (parallel): bits/contexts -> per-position adaptive frequency f (12b)
// Phase 2 (sequential, 1 lane): arithmetic coder; batched renorm + batched
//         bit-append, scalarized via readfirstlane. Blocks 1..256 are BALLAST:
//         they spin on a flag to keep SCLK boosted (clock-throttle experiment).
// Phase 3 (parallel): bytes -> int32 outputs (harness reads d_out as int32)
//
// ws layout (bytes):
//   0       : hdr[2]  (nbits, nwords)
//   2048    : flag    (u32, ballast exit flag)
//   4096    : outw    (262144 B bitstream buffer = 2^21 bits)
//   266240  : histG   (256 blocks * 512 keys * u32)
//   790528  : offsG   (same shape, exclusive scan over blocks)
//   1314816 : keys    (u16 * 2^20)  key = state<<1 | bit
//   3411968 : fb      (u16 * 2^20)  f | bit<<15

#define N_TOT (1 << 20)
#define BLK_ELEMS 4096
#define N_BLKS (N_TOT / BLK_ELEMS)   // 256

__global__ void k_keys(const float* __restrict__ sym, unsigned short* __restrict__ keys) {
    int t = blockIdx.x * blockDim.x + threadIdx.x;
    if (t >= N_TOT) return;
    unsigned s = 0;
#pragma unroll
    for (int i = 1; i <= 8; ++i) {
        unsigned b = (t >= i) ? (sym[t - i] > 0.0f ? 1u : 0u) : 0u;
        s |= b << (i - 1);
    }
    unsigned bit = sym[t] > 0.0f ? 1u : 0u;
    keys[t] = (unsigned short)((s << 1) | bit);
}

__global__ void k_hist(const unsigned short* __restrict__ keys, unsigned* __restrict__ histG) {
    __shared__ unsigned h[512];
    for (int i = threadIdx.x; i < 512; i += blockDim.x) h[i] = 0;
    __syncthreads();
    int base = blockIdx.x * BLK_ELEMS;
    for (int i = threadIdx.x; i < BLK_ELEMS; i += blockDim.x)
        atomicAdd(&h[keys[base + i]], 1u);
    __syncthreads();
    for (int i = threadIdx.x; i < 512; i += blockDim.x)
        histG[blockIdx.x * 512 + i] = h[i];
}

__global__ void k_scan(const unsigned* __restrict__ histG, unsigned* __restrict__ offsG,
                       unsigned* __restrict__ flag) {
    int k = blockIdx.x * blockDim.x + threadIdx.x;
    if (k == 0) __hip_atomic_store(flag, 0u, __ATOMIC_RELAXED, __HIP_MEMORY_SCOPE_AGENT);
    if (k >= 512) return;
    unsigned run = 0;
    for (int b = 0; b < N_BLKS; ++b) {
        offsG[b * 512 + k] = run;
        run += histG[b * 512 + k];
    }
}

__global__ __launch_bounds__(64) void k_freq(const unsigned short* __restrict__ keys,
                                             const unsigned* __restrict__ offsG,
                                             unsigned short* __restrict__ fb) {
    __shared__ unsigned cnt[512];
    int lane = threadIdx.x;
    for (int i = lane; i < 512; i += 64) cnt[i] = offsG[blockIdx.x * 512 + i];
    __syncthreads();
    int base = blockIdx.x * BLK_ELEMS;
    unsigned long long ltm = (1ull << lane) - 1ull;
    for (int c = 0; c < BLK_ELEMS / 64; ++c) {
        int t = base + c * 64 + lane;
        unsigned key = keys[t];
        unsigned bit = key & 1u;
        unsigned state = key >> 1;
        unsigned long long eq = ~0ull;
#pragma unroll
        for (int b = 0; b < 8; ++b) {
            unsigned long long mb = __ballot((state >> b) & 1u);
            eq &= ((state >> b) & 1u) ? mb : ~mb;
        }
        unsigned long long bb = __ballot(bit);
        unsigned long long same = eq & (bit ? bb : ~bb);
        unsigned long long sib  = eq & (bit ? ~bb : bb);
        unsigned base_same = cnt[key];
        unsigned base_sib  = cnt[key ^ 1u];
        __syncthreads();
        unsigned c_same = base_same + (unsigned)__popcll(same & ltm);
        unsigned c_sib  = base_sib  + (unsigned)__popcll(sib & ltm);
        unsigned long long a0 = 1ull + (unsigned long long)(bit ? c_sib : c_same);
        unsigned long long a1 = 1ull + (unsigned long long)(bit ? c_same : c_sib);
        double p0 = (double)a0 / (double)(a0 + a1);
        double fd = rint(p0 * 4094.0) + 1.0;
        fd = fd < 1.0 ? 1.0 : (fd > 4095.0 ? 4095.0 : fd);
        unsigned f = (unsigned)fd;
        fb[t] = (unsigned short)(f | (bit << 15));
        int hi = 63 - __builtin_clzll(same);
        if (lane == hi) cnt[key] = base_same + (unsigned)__popcll(same);
        __syncthreads();
    }
}

__global__ __launch_bounds__(256) void k_encode(const unsigned short* __restrict__ fb,
                                                unsigned* __restrict__ outw,
                                                unsigned* __restrict__ hdr,
                                                unsigned* __restrict__ flag) {
    if (blockIdx.x != 0) {
        // ---- ballast: keep SCLK boosted while the serial encoder runs ----
        float x = 1.0f + (float)threadIdx.x;
        while (__hip_atomic_load(flag, __ATOMIC_RELAXED, __HIP_MEMORY_SCOPE_AGENT) == 0u) {
#pragma unroll 1
            for (int i = 0; i < 128; ++i) x = __builtin_fmaf(x, 1.0000001f, 1.0e-7f);
            asm volatile("" :: "v"(x));
        }
        asm volatile("" :: "v"(x));
        return;
    }
    if (threadIdx.x != 0) return;
    unsigned low = 0u, high = 0xFFFFFFFFu;
    unsigned pending = 0, nb = 0, nacc = 0, wp = 0;
    unsigned long long acc = 0;

    auto EMIT1 = [&](unsigned b) {
        acc = (acc << 1) | (unsigned long long)b; ++nacc; ++nb;
        if (nacc >= 32u) {
            outw[wp++] = __builtin_bswap32((unsigned)(acc >> (nacc - 32u)));
            nacc -= 32u;
        }
    };

    const uint4* p = (const uint4*)fb;
    uint4 A = p[0], B = p[1];                // chunk 0 preload (16 symbols)
    const int NC = N_TOT / 16;
    for (int c = 0; c < NC; ++c) {
        unsigned sw[8];
        sw[0] = __builtin_amdgcn_readfirstlane(A.x);
        sw[1] = __builtin_amdgcn_readfirstlane(A.y);
        sw[2] = __builtin_amdgcn_readfirstlane(A.z);
        sw[3] = __builtin_amdgcn_readfirstlane(A.w);
        sw[4] = __builtin_amdgcn_readfirstlane(B.x);
        sw[5] = __builtin_amdgcn_readfirstlane(B.y);
        sw[6] = __builtin_amdgcn_readfirstlane(B.z);
        sw[7] = __builtin_amdgcn_readfirstlane(B.w);
        if (c + 1 < NC) { A = p[2 * c + 2]; B = p[2 * c + 3]; }  // prefetch next chunk
#pragma unroll
        for (int j = 0; j < 16; ++j) {
            unsigned val = (sw[j >> 1] >> ((j & 1) << 4)) & 0xFFFFu;
            unsigned f = val & 0xFFFu;
            unsigned bitv = val >> 15;
            // interval narrowing: split = low + ((high-low+1)*f) >> 12
            unsigned r = high - low;                       // rng - 1
            unsigned plo = r * f;
            unsigned phi = __umulhi(r, f);
            unsigned long long prod = (((unsigned long long)phi << 32) | plo) + f;
            unsigned split = low + (unsigned)(prod >> 12);
            high = bitv ? high : (split - 1u);
            low  = bitv ? split : low;
            // batched common-MSB emission: k bits + pending complements, one append
            unsigned x = low ^ high;                       // never 0 (rng > 2^18)
            unsigned k = (unsigned)__builtin_clz(x);       // 0..31
            if (k) {
                unsigned b0 = low >> 31;
                unsigned Lb = k + pending;
                if (Lb <= 32u) {
                    // payload = b0 | pending x (~b0) | bits 1..k-1 of low (MSB-first)
                    unsigned long long t =
                        (((unsigned long long)low) >> (32u - k)) & ((1ull << (k - 1u)) - 1ull);
                    unsigned long long comp =
                        b0 ? 0ull : (((1ull << pending) - 1ull) << (k - 1u));
                    unsigned long long V = ((unsigned long long)b0 << (Lb - 1u)) | comp | t;
                    acc = (acc << Lb) | V; nacc += Lb; nb += Lb;
                    if (nacc >= 32u) {
                        outw[wp++] = __builtin_bswap32((unsigned)(acc >> (nacc - 32u)));
                        nacc -= 32u;
                    }
                } else {                                   // rare: long pending run
                    EMIT1(b0);
                    unsigned pd = pending;
                    while (pd) { EMIT1(1u - b0); --pd; }
                    for (unsigned i = 1; i < k; ++i) EMIT1((low >> (31u - i)) & 1u);
                }
                pending = 0;
                low <<= k;
                high = (high << k) | ((1u << k) - 1u);     // k <= 31
            }
            // batched E3 (straddle) steps, unconditional (m=0 is identity)
            unsigned nt1 = ~(low << 1);                    // LSB=1 -> nonzero
            unsigned t2g = (high << 1) | 1u;               // |1 guards t2==0 (proof: a<=31)
            unsigned a  = (unsigned)__builtin_clz(nt1);
            unsigned bq = (unsigned)__builtin_clz(t2g);
            unsigned m = a < bq ? a : bq;                  // 0..31
            pending += m;
            unsigned long long pm1 = (1ull << m) - 1ull;
            low  = (unsigned)((((unsigned long long)low)  << m) - (pm1 << 31));
            high = (unsigned)(((((unsigned long long)high) << m) - (pm1 << 31)) + pm1);
        }
    }
    // flush
    pending += 1u;
    unsigned fbit = (low >= 0x40000000u) ? 1u : 0u;
    EMIT1(fbit);
    while (pending) { EMIT1(1u - fbit); --pending; }
    if (nacc) outw[wp++] = __builtin_bswap32((unsigned)(acc << (32u - nacc)));
    hdr[0] = nb;
    hdr[1] = wp;
    __hip_atomic_store(flag, 1u, __ATOMIC_RELEASE, __HIP_MEMORY_SCOPE_AGENT);
}

__global__ void k_out(const unsigned char* __restrict__ bytes,
                      const unsigned* __restrict__ hdr, int* __restrict__ out) {
    int i = blockIdx.x * blockDim.x + threadIdx.x;
    if (i > 262144) return;
    if (i == 262144) { out[i] = (int)hdr[0]; return; }
    unsigned nbytes = hdr[1] * 4u;
    out[i] = ((unsigned)i < nbytes) ? (int)bytes[i] : 0;
}

extern "C" void kernel_launch(void* const* d_in, const int* in_sizes, int n_in,
                              void* d_out, int out_size, void* d_ws, size_t ws_size,
                              hipStream_t stream) {
    (void)in_sizes; (void)n_in; (void)out_size; (void)ws_size;
    const float* sym = (const float*)d_in[0];
    int* out = (int*)d_out;
    char* ws = (char*)d_ws;
    unsigned*       hdr   = (unsigned*)(ws);
    unsigned*       flag  = (unsigned*)(ws + 2048);
    unsigned*       outw  = (unsigned*)(ws + 4096);
    unsigned*       histG = (unsigned*)(ws + 266240);
    unsigned*       offsG = (unsigned*)(ws + 790528);
    unsigned short* keys  = (unsigned short*)(ws + 1314816);
    unsigned short* fb    = (unsigned short*)(ws + 3411968);

    k_keys<<<N_TOT / 256, 256, 0, stream>>>(sym, keys);
    k_hist<<<N_BLKS, 256, 0, stream>>>(keys, histG);
    k_scan<<<1, 512, 0, stream>>>(histG, offsG, flag);
    k_freq<<<N_BLKS, 64, 0, stream>>>(keys, offsG, fb);
    k_encode<<<257, 256, 0, stream>>>(fb, outw, hdr, flag);
    k_out<<<1025, 256, 0, stream>>>((const unsigned char*)outw, hdr, out);
}

// Round 9
// 74088.025 us; speedup vs baseline: 1.6451x; 1.6451x over previous
//
#include <hip/hip_runtime.h>
#include <hip/hip_bf16.h>

// Adaptive binary arithmetic encoder, bit-exact port of the JAX reference.
// Phase 1 (parallel): bits/contexts -> per-position frequency f (12b)
// Phase 2 (serial, 1 lane): MINIMAL state chain (low, high) only; per symbol
//         records (tb = top-k bits of low, k = emit count, m = E3 count),
//         branchless, bit-materialization fully deferred.
// Phase 3 (parallel): prefix-sums over (k, m) reconstruct pending/offsets;
//         payloads written via atomicOr into pre-zeroed bit buffer.
// Phase 4 (parallel): bytes -> int32 outputs.
//
// ws layout (bytes):
//   0       : hdr     ([0]=nbits, [2]=final low)
//   4096    : outw    (262144 B bitstream buffer, pre-zeroed each call)
//   266240  : kmrec   (u8  * 2^20)  k | m<<4            (dead histG region)
//   1314816 : tbrec   (u16 * 2^20)  top-k bits of low   (dead keys region)
//   3411968 : fb      (u16 * 2^20)  f | bit<<15  -- dead after k_enc2:
//   3411968 : binfo   (uint4 * 256)  reused over dead fb
//   3416064 : Sb, 3417088: Kb, 3418112: Pb  (u32 * 256 each)

#define N_TOT (1 << 20)
#define BLK_ELEMS 4096
#define N_BLKS (N_TOT / BLK_ELEMS)   // 256

__global__ void k_zero(unsigned* __restrict__ outw) {
    outw[blockIdx.x * 256 + threadIdx.x] = 0u;   // 256 blocks x 256 = 65536 words
}

__global__ void k_keys(const float* __restrict__ sym, unsigned short* __restrict__ keys) {
    int t = blockIdx.x * blockDim.x + threadIdx.x;
    if (t >= N_TOT) return;
    unsigned s = 0;
#pragma unroll
    for (int i = 1; i <= 8; ++i) {
        unsigned b = (t >= i) ? (sym[t - i] > 0.0f ? 1u : 0u) : 0u;
        s |= b << (i - 1);
    }
    unsigned bit = sym[t] > 0.0f ? 1u : 0u;
    keys[t] = (unsigned short)((s << 1) | bit);
}

__global__ void k_hist(const unsigned short* __restrict__ keys, unsigned* __restrict__ histG) {
    __shared__ unsigned h[512];
    for (int i = threadIdx.x; i < 512; i += blockDim.x) h[i] = 0;
    __syncthreads();
    int base = blockIdx.x * BLK_ELEMS;
    for (int i = threadIdx.x; i < BLK_ELEMS; i += blockDim.x)
        atomicAdd(&h[keys[base + i]], 1u);
    __syncthreads();
    for (int i = threadIdx.x; i < 512; i += blockDim.x)
        histG[blockIdx.x * 512 + i] = h[i];
}

__global__ void k_scan(const unsigned* __restrict__ histG, unsigned* __restrict__ offsG) {
    int k = blockIdx.x * blockDim.x + threadIdx.x;
    if (k >= 512) return;
    unsigned run = 0;
    for (int b = 0; b < N_BLKS; ++b) {
        offsG[b * 512 + k] = run;
        run += histG[b * 512 + k];
    }
}

__global__ __launch_bounds__(64) void k_freq(const unsigned short* __restrict__ keys,
                                             const unsigned* __restrict__ offsG,
                                             unsigned short* __restrict__ fb) {
    __shared__ unsigned cnt[512];
    int lane = threadIdx.x;
    for (int i = lane; i < 512; i += 64) cnt[i] = offsG[blockIdx.x * 512 + i];
    __syncthreads();
    int base = blockIdx.x * BLK_ELEMS;
    unsigned long long ltm = (1ull << lane) - 1ull;
    for (int c = 0; c < BLK_ELEMS / 64; ++c) {
        int t = base + c * 64 + lane;
        unsigned key = keys[t];
        unsigned bit = key & 1u;
        unsigned state = key >> 1;
        unsigned long long eq = ~0ull;
#pragma unroll
        for (int b = 0; b < 8; ++b) {
            unsigned long long mb = __ballot((state >> b) & 1u);
            eq &= ((state >> b) & 1u) ? mb : ~mb;
        }
        unsigned long long bb = __ballot(bit);
        unsigned long long same = eq & (bit ? bb : ~bb);
        unsigned long long sib  = eq & (bit ? ~bb : bb);
        unsigned base_same = cnt[key];
        unsigned base_sib  = cnt[key ^ 1u];
        __syncthreads();
        unsigned c_same = base_same + (unsigned)__popcll(same & ltm);
        unsigned c_sib  = base_sib  + (unsigned)__popcll(sib & ltm);
        unsigned long long a0 = 1ull + (unsigned long long)(bit ? c_sib : c_same);
        unsigned long long a1 = 1ull + (unsigned long long)(bit ? c_same : c_sib);
        double p0 = (double)a0 / (double)(a0 + a1);
        double fd = rint(p0 * 4094.0) + 1.0;
        fd = fd < 1.0 ? 1.0 : (fd > 4095.0 ? 4095.0 : fd);
        unsigned f = (unsigned)fd;
        fb[t] = (unsigned short)(f | (bit << 15));
        int hi = 63 - __builtin_clzll(same);
        if (lane == hi) cnt[key] = base_same + (unsigned)__popcll(same);
        __syncthreads();
    }
}

// Serial state chain only. Per symbol: narrow, k = clz(low^high),
// m = clz(~(low<<(k+1)) | (high<<(k+1))), fused K-shift. Branchless.
// f in [1,4095] => range >= 2^18 => k,m <= 14 (all 32-bit shifts safe).
__global__ __launch_bounds__(64) void k_enc2(const unsigned short* __restrict__ fb,
                                             unsigned short* __restrict__ tbrec,
                                             unsigned char* __restrict__ kmrec,
                                             unsigned* __restrict__ hdr) {
    if (threadIdx.x != 0 || blockIdx.x != 0) return;
    unsigned low = 0u, high = 0xFFFFFFFFu;
    const uint4* p = (const uint4*)fb;
    uint4 A = p[0], B = p[1];
    const int NC = N_TOT / 16;
    for (int c = 0; c < NC; ++c) {
        unsigned sw[8];
        sw[0] = __builtin_amdgcn_readfirstlane(A.x);
        sw[1] = __builtin_amdgcn_readfirstlane(A.y);
        sw[2] = __builtin_amdgcn_readfirstlane(A.z);
        sw[3] = __builtin_amdgcn_readfirstlane(A.w);
        sw[4] = __builtin_amdgcn_readfirstlane(B.x);
        sw[5] = __builtin_amdgcn_readfirstlane(B.y);
        sw[6] = __builtin_amdgcn_readfirstlane(B.z);
        sw[7] = __builtin_amdgcn_readfirstlane(B.w);
        if (c + 1 < NC) { A = p[2 * c + 2]; B = p[2 * c + 3]; }
        int base = c * 16;
#pragma unroll
        for (int j = 0; j < 16; ++j) {
            unsigned val = (sw[j >> 1] >> ((j & 1) << 4)) & 0xFFFFu;
            unsigned f = val & 0xFFFu;
            unsigned bitv = val >> 15;
            unsigned r = high - low;                           // rng - 1
            unsigned long long prod = (unsigned long long)r * f + f;   // rng*f
            unsigned split = low + (unsigned)(prod >> 12);
            high = bitv ? high : (split - 1u);
            low  = bitv ? split : low;
            unsigned D = low ^ high;                           // != 0 (rng >= 2^18)
            unsigned k = (unsigned)__builtin_clz(D);           // 0..14
            unsigned tb = (unsigned)(((unsigned long long)low) >> (32u - k));
            unsigned kp1 = k + 1u;
            unsigned m = (unsigned)__builtin_clz((~(low << kp1)) | (high << kp1)); // 0..14
            unsigned K = k + m;
            unsigned sub = m ? 0x80000000u : 0u;
            low  = (low << K) ^ sub;
            high = ((high << K) + ((1u << K) - 1u)) ^ sub;
            tbrec[base + j] = (unsigned short)tb;
            kmrec[base + j] = (unsigned char)(k | (m << 4));
        }
    }
    hdr[2] = low;
}

// Per-block sums of m, k; flag + m-prefix-before-last-emitter.
__global__ __launch_bounds__(256) void k_bsum(const unsigned char* __restrict__ km,
                                              uint4* __restrict__ binfo) {
    __shared__ unsigned Lsm[256], Lsk[256], Le[256], Lmb[256];
    int t = threadIdx.x, b = blockIdx.x;
    uint4 raw = *(const uint4*)(km + b * 4096 + t * 16);
    unsigned bytes[4] = {raw.x, raw.y, raw.z, raw.w};
    unsigned sm = 0, sk = 0, e = 0, mb = 0;
#pragma unroll
    for (int w = 0; w < 4; ++w)
#pragma unroll
        for (int i = 0; i < 4; ++i) {
            unsigned v = (bytes[w] >> (8 * i)) & 0xFFu;
            unsigned k = v & 15u, m = v >> 4;
            if (k) { mb = sm; e = 1u; }
            sm += m; sk += k;
        }
    Lsm[t] = sm; Lsk[t] = sk; Le[t] = e; Lmb[t] = mb;
    __syncthreads();
    if (t == 0) {
        unsigned s = 0, K = 0, E = 0, MB = 0;
        for (int i = 0; i < 256; ++i) {
            if (Le[i]) { MB = s + Lmb[i]; E = 1u; }
            s += Lsm[i]; K += Lsk[i];
        }
        binfo[b] = make_uint4(s, K, E, MB);
    }
}

// Sequential cross-block carries + flush bits + nbits.
__global__ void k_carry(const uint4* __restrict__ binfo,
                        unsigned* __restrict__ Sb, unsigned* __restrict__ Kb,
                        unsigned* __restrict__ Pb, unsigned* __restrict__ hdr,
                        unsigned* __restrict__ outw) {
    if (threadIdx.x != 0 || blockIdx.x != 0) return;
    unsigned S = 0, K = 0, PB = 0;
    for (int b = 0; b < 256; ++b) {
        Sb[b] = S; Kb[b] = K; Pb[b] = PB;
        uint4 v = binfo[b];
        if (v.z) PB = S + v.w;
        S += v.x; K += v.y;
    }
    unsigned pendf = S - PB;
    unsigned lowf = hdr[2];
    unsigned fbit = (lowf >= 0x40000000u) ? 1u : 0u;
    unsigned offe = K + PB;
    hdr[0] = offe + 2u + pendf;
    if (fbit) {
        atomicOr(&outw[offe >> 5], __builtin_bswap32(1u << (31u - (offe & 31u))));
    } else {
        unsigned o = offe + 1u, n = pendf + 1u;      // run of 1s
        while (n) {
            unsigned so = o & 31u;
            unsigned take = (n < 32u - so) ? n : (32u - so);
            unsigned be = (unsigned)((((1ull << take) - 1ull) << (32u - so - take)));
            atomicOr(&outw[o >> 5], __builtin_bswap32(be));
            o += take; n -= take;
        }
    }
}

// Parallel payload expansion: each emitting symbol writes
// b0, pend complements of b0, then (k-1) low bits, at its exact bit offset.
__global__ __launch_bounds__(256) void k_expand(const unsigned short* __restrict__ tb16,
                                                const unsigned char* __restrict__ km,
                                                const unsigned* __restrict__ Sb,
                                                const unsigned* __restrict__ Kb,
                                                const unsigned* __restrict__ Pb,
                                                unsigned* __restrict__ outw) {
    __shared__ unsigned Lsm[256], Lsk[256], Le[256], Lmb[256];
    __shared__ unsigned Ps[256], Pk[256], Pp[256];
    int t = threadIdx.x, b = blockIdx.x;
    uint4 raw = *(const uint4*)(km + b * 4096 + t * 16);
    unsigned bytes[4] = {raw.x, raw.y, raw.z, raw.w};
    unsigned kv[16], mv[16];
    unsigned sm = 0, sk = 0, e = 0, mb = 0;
#pragma unroll
    for (int w = 0; w < 4; ++w)
#pragma unroll
        for (int i = 0; i < 4; ++i) {
            unsigned v = (bytes[w] >> (8 * i)) & 0xFFu;
            unsigned k = v & 15u, m = v >> 4;
            kv[w * 4 + i] = k; mv[w * 4 + i] = m;
            if (k) { mb = sm; e = 1u; }
            sm += m; sk += k;
        }
    Lsm[t] = sm; Lsk[t] = sk; Le[t] = e; Lmb[t] = mb;
    __syncthreads();
    if (t == 0) {
        unsigned s = Sb[b], K = Kb[b], pb = Pb[b];
        for (int i = 0; i < 256; ++i) {
            Ps[i] = s; Pk[i] = K; Pp[i] = pb;
            if (Le[i]) pb = s + Lmb[i];
            s += Lsm[i]; K += Lsk[i];
        }
    }
    __syncthreads();
    unsigned s = Ps[t], kk = Pk[t], pb = Pp[t];
    const unsigned short* tq = tb16 + b * 4096 + t * 16;
#pragma unroll
    for (int j = 0; j < 16; ++j) {
        unsigned k = kv[j], m = mv[j];
        if (k) {
            unsigned tb = tq[j];
            unsigned pend = s - pb;
            unsigned off = kk + pb;
            unsigned b0 = (tb >> (k - 1u)) & 1u;
            if (b0) {
                atomicOr(&outw[off >> 5], __builtin_bswap32(1u << (31u - (off & 31u))));
            } else if (pend) {                       // run of pend 1s at off+1
                unsigned o = off + 1u, n = pend;
                while (n) {
                    unsigned so = o & 31u;
                    unsigned take = (n < 32u - so) ? n : (32u - so);
                    unsigned be = (unsigned)((((1ull << take) - 1ull) << (32u - so - take)));
                    atomicOr(&outw[o >> 5], __builtin_bswap32(be));
                    o += take; n -= take;
                }
            }
            unsigned wid = k - 1u;
            if (wid) {
                unsigned rest = tb & ((1u << wid) - 1u);
                if (rest) {
                    unsigned o = off + 1u + pend;
                    unsigned end = (o & 31u) + wid;          // <= 45
                    unsigned long long Av = (unsigned long long)rest << (64u - end);
                    unsigned hi = (unsigned)(Av >> 32);
                    unsigned lo2 = (unsigned)Av;
                    if (hi)  atomicOr(&outw[o >> 5], __builtin_bswap32(hi));
                    if (lo2) atomicOr(&outw[(o >> 5) + 1u], __builtin_bswap32(lo2));
                }
            }
            pb = s;
        }
        s += m; kk += k;
    }
}

__global__ void k_out(const unsigned char* __restrict__ bytes,
                      const unsigned* __restrict__ hdr, int* __restrict__ out) {
    int i = blockIdx.x * blockDim.x + threadIdx.x;
    if (i > 262144) return;
    if (i == 262144) { out[i] = (int)hdr[0]; return; }
    out[i] = (int)bytes[i];                 // buffer pre-zeroed; tail bytes are 0
}

extern "C" void kernel_launch(void* const* d_in, const int* in_sizes, int n_in,
                              void* d_out, int out_size, void* d_ws, size_t ws_size,
                              hipStream_t stream) {
    (void)in_sizes; (void)n_in; (void)out_size; (void)ws_size;
    const float* sym = (const float*)d_in[0];
    int* out = (int*)d_out;
    char* ws = (char*)d_ws;
    unsigned*       hdr   = (unsigned*)(ws);
    unsigned*       outw  = (unsigned*)(ws + 4096);
    unsigned*       histG = (unsigned*)(ws + 266240);
    unsigned*       offsG = (unsigned*)(ws + 790528);
    unsigned short* keys  = (unsigned short*)(ws + 1314816);
    unsigned short* fb    = (unsigned short*)(ws + 3411968);
    unsigned char*  kmrec = (unsigned char*)(ws + 266240);    // over dead histG/offsG
    unsigned short* tbrec = (unsigned short*)(ws + 1314816);  // over dead keys
    uint4*          binfo = (uint4*)(ws + 3411968);           // over dead fb
    unsigned*       Sb    = (unsigned*)(ws + 3416064);
    unsigned*       Kb    = (unsigned*)(ws + 3417088);
    unsigned*       Pb    = (unsigned*)(ws + 3418112);

    k_zero<<<256, 256, 0, stream>>>(outw);
    k_keys<<<N_TOT / 256, 256, 0, stream>>>(sym, keys);
    k_hist<<<N_BLKS, 256, 0, stream>>>(keys, histG);
    k_scan<<<1, 512, 0, stream>>>(histG, offsG);
    k_freq<<<N_BLKS, 64, 0, stream>>>(keys, offsG, fb);
    k_enc2<<<1, 64, 0, stream>>>(fb, tbrec, kmrec, hdr);
    k_bsum<<<256, 256, 0, stream>>>(kmrec, binfo);
    k_carry<<<1, 64, 0, stream>>>(binfo, Sb, Kb, Pb, hdr, outw);
    k_expand<<<256, 256, 0, stream>>>(tbrec, kmrec, Sb, Kb, Pb, outw);
    k_out<<<1025, 256, 0, stream>>>((const unsigned char*)outw, hdr, out);
}

// Round 10
// 61585.687 us; speedup vs baseline: 1.9790x; 1.2030x over previous
//
#include <hip/hip_runtime.h>
#include <hip/hip_bf16.h>

// Adaptive binary arithmetic encoder, bit-exact port of the JAX reference.
// Round-10 architecture ("G-sum"): the emitted stream equals the binary
// expansion of M = (N - N%2^32) + 2^(30+fbit), where
//   N = sum over bit=1 symbols of d_i * 2^(p_end - p_i),
//   d_i = (rng_i * f_i) >> 12,  p_i = total renorm shifts before symbol i,
//   fbit = bit30 of N,  nbits = p_end + 2.
// (Pending-complements == carry propagation; verified on worked examples.)
//
// Phase 1 (parallel): bits/contexts -> per-position frequency f (12b)   [verified]
// Phase 2 (serial, 1 lane): minimal (low, high, p) chain; stores only
//         per-256-symbol boundary states (low, high, p). No per-symbol stores.
// Phase 3 (parallel): 4096 chunks re-run the chain from boundary states,
//         atomicAdd d<<((p_end-p)&31) into u64 limb accumulators.
// Phase 4 (serial-small): ripple-carry limbs -> res[]; flush: res[0]=2^(30+fbit).
// Phase 5 (parallel): out bytes = (M >> (p_end+24-8q)) & 0xFF; out[2^18]=nbits.
//
// ws layout (bytes):
//   0       : hdr     ([0]=nbits, [1]=p_end)
//   266240  : limb    (u64 * 65552)  over dead histG/offsG      (ends 790656)
//   790656  : res     (u32 * 65552)                              (ends 1052864)
//   1314816 : bnd     (uint4 * 4096) over dead keys              (ends 1380352)
//   266240  : histG / 790528 : offsG / 1314816 : keys   (live until k_freq)
//   3411968 : fb      (u16 * 2^20)  f | bit<<15

#define N_TOT (1 << 20)
#define BLK_ELEMS 4096
#define N_BLKS (N_TOT / BLK_ELEMS)   // 256
#define NLIMB 65552

__global__ void k_keys(const float* __restrict__ sym, unsigned short* __restrict__ keys) {
    int t = blockIdx.x * blockDim.x + threadIdx.x;
    if (t >= N_TOT) return;
    unsigned s = 0;
#pragma unroll
    for (int i = 1; i <= 8; ++i) {
        unsigned b = (t >= i) ? (sym[t - i] > 0.0f ? 1u : 0u) : 0u;
        s |= b << (i - 1);
    }
    unsigned bit = sym[t] > 0.0f ? 1u : 0u;
    keys[t] = (unsigned short)((s << 1) | bit);
}

__global__ void k_hist(const unsigned short* __restrict__ keys, unsigned* __restrict__ histG) {
    __shared__ unsigned h[512];
    for (int i = threadIdx.x; i < 512; i += blockDim.x) h[i] = 0;
    __syncthreads();
    int base = blockIdx.x * BLK_ELEMS;
    for (int i = threadIdx.x; i < BLK_ELEMS; i += blockDim.x)
        atomicAdd(&h[keys[base + i]], 1u);
    __syncthreads();
    for (int i = threadIdx.x; i < 512; i += blockDim.x)
        histG[blockIdx.x * 512 + i] = h[i];
}

__global__ void k_scan(const unsigned* __restrict__ histG, unsigned* __restrict__ offsG) {
    int k = blockIdx.x * blockDim.x + threadIdx.x;
    if (k >= 512) return;
    unsigned run = 0;
    for (int b = 0; b < N_BLKS; ++b) {
        offsG[b * 512 + k] = run;
        run += histG[b * 512 + k];
    }
}

__global__ __launch_bounds__(64) void k_freq(const unsigned short* __restrict__ keys,
                                             const unsigned* __restrict__ offsG,
                                             unsigned short* __restrict__ fb) {
    __shared__ unsigned cnt[512];
    int lane = threadIdx.x;
    for (int i = lane; i < 512; i += 64) cnt[i] = offsG[blockIdx.x * 512 + i];
    __syncthreads();
    int base = blockIdx.x * BLK_ELEMS;
    unsigned long long ltm = (1ull << lane) - 1ull;
    for (int c = 0; c < BLK_ELEMS / 64; ++c) {
        int t = base + c * 64 + lane;
        unsigned key = keys[t];
        unsigned bit = key & 1u;
        unsigned state = key >> 1;
        unsigned long long eq = ~0ull;
#pragma unroll
        for (int b = 0; b < 8; ++b) {
            unsigned long long mb = __ballot((state >> b) & 1u);
            eq &= ((state >> b) & 1u) ? mb : ~mb;
        }
        unsigned long long bb = __ballot(bit);
        unsigned long long same = eq & (bit ? bb : ~bb);
        unsigned long long sib  = eq & (bit ? ~bb : bb);
        unsigned base_same = cnt[key];
        unsigned base_sib  = cnt[key ^ 1u];
        __syncthreads();
        unsigned c_same = base_same + (unsigned)__popcll(same & ltm);
        unsigned c_sib  = base_sib  + (unsigned)__popcll(sib & ltm);
        unsigned long long a0 = 1ull + (unsigned long long)(bit ? c_sib : c_same);
        unsigned long long a1 = 1ull + (unsigned long long)(bit ? c_same : c_sib);
        double p0 = (double)a0 / (double)(a0 + a1);
        double fd = rint(p0 * 4094.0) + 1.0;
        fd = fd < 1.0 ? 1.0 : (fd > 4095.0 ? 4095.0 : fd);
        unsigned f = (unsigned)fd;
        fb[t] = (unsigned short)(f | (bit << 15));
        int hi = 63 - __builtin_clzll(same);
        if (lane == hi) cnt[key] = base_same + (unsigned)__popcll(same);
        __syncthreads();
    }
}

__global__ void k_zerol(unsigned long long* __restrict__ limb) {
    int i = blockIdx.x * 256 + threadIdx.x;
    if (i < NLIMB) limb[i] = 0ull;
}

// Serial minimal chain: (low, high, p). Boundary state stored every 256 symbols.
__global__ __launch_bounds__(64) void k_enc3(const unsigned short* __restrict__ fb,
                                             uint4* __restrict__ bnd,
                                             unsigned* __restrict__ hdr) {
    if (threadIdx.x != 0 || blockIdx.x != 0) return;
    unsigned low = 0u, high = 0xFFFFFFFFu, pp = 0u;
    const uint4* pq = (const uint4*)fb;
    uint4 A = pq[0], B = pq[1];
    const int NC = N_TOT / 16;
    for (int cc = 0; cc < NC; ++cc) {
        if ((cc & 15) == 0) bnd[cc >> 4] = make_uint4(low, high, pp, 0u);
        unsigned sw[8];
        sw[0] = __builtin_amdgcn_readfirstlane(A.x);
        sw[1] = __builtin_amdgcn_readfirstlane(A.y);
        sw[2] = __builtin_amdgcn_readfirstlane(A.z);
        sw[3] = __builtin_amdgcn_readfirstlane(A.w);
        sw[4] = __builtin_amdgcn_readfirstlane(B.x);
        sw[5] = __builtin_amdgcn_readfirstlane(B.y);
        sw[6] = __builtin_amdgcn_readfirstlane(B.z);
        sw[7] = __builtin_amdgcn_readfirstlane(B.w);
        if (cc + 1 < NC) { A = pq[2 * cc + 2]; B = pq[2 * cc + 3]; }
#pragma unroll
        for (int j = 0; j < 16; ++j) {
            unsigned val = (sw[j >> 1] >> ((j & 1) << 4)) & 0xFFFFu;
            unsigned f = val & 0xFFFu;
            unsigned bitv = val >> 15;
            unsigned r = high - low;                         // rng - 1
            unsigned long long prod = (unsigned long long)r * f + f;   // rng*f
            unsigned d = (unsigned)(prod >> 12);
            unsigned split = low + d;
            high = bitv ? high : (split - 1u);
            low  = bitv ? split : low;
            unsigned D = low ^ high;                         // != 0 (rng >= 2^18)
            unsigned k = (unsigned)__builtin_clz(D);
            unsigned kp1 = k + 1u;
            unsigned m = (unsigned)__builtin_clz((~(low << kp1)) | (high << kp1));
            unsigned K = k + m;
            pp += K;
            unsigned sub = m ? 0x80000000u : 0u;
            low  = (low << K) ^ sub;
            high = ((high << K) + ((1u << K) - 1u)) ^ sub;
        }
    }
    hdr[1] = pp;   // p_end
}

// 4096 parallel chunks: re-run chain from boundary state; accumulate d<<sh.
__global__ __launch_bounds__(256) void k_chunk(const unsigned short* __restrict__ fb,
                                               const uint4* __restrict__ bnd,
                                               const unsigned* __restrict__ hdr,
                                               unsigned long long* __restrict__ limb) {
    int c = blockIdx.x * 256 + threadIdx.x;   // 0..4095
    uint4 s = bnd[c];
    unsigned low = s.x, high = s.y, pp = s.z;
    unsigned pend = hdr[1];
    const unsigned* fw = (const unsigned*)fb;
    int base = c * 256;
    for (int i = 0; i < 256; i += 2) {
        unsigned w = fw[(base + i) >> 1];
#pragma unroll
        for (int h = 0; h < 2; ++h) {
            unsigned val = (w >> (h * 16)) & 0xFFFFu;
            unsigned f = val & 0xFFFu;
            unsigned bitv = val >> 15;
            unsigned r = high - low;
            unsigned long long prod = (unsigned long long)r * f + f;
            unsigned d = (unsigned)(prod >> 12);
            unsigned split = low + d;
            if (bitv) {                                     // contribution at scale pp
                unsigned sh = pend - pp;
                unsigned long long v = (unsigned long long)d << (sh & 31u);
                unsigned j = sh >> 5;
                atomicAdd(&limb[j], v & 0xFFFFFFFFull);
                unsigned long long vh = v >> 32;
                if (vh) atomicAdd(&limb[j + 1], vh);
            }
            high = bitv ? high : (split - 1u);
            low  = bitv ? split : low;
            unsigned D = low ^ high;
            unsigned k = (unsigned)__builtin_clz(D);
            unsigned kp1 = k + 1u;
            unsigned m = (unsigned)__builtin_clz((~(low << kp1)) | (high << kp1));
            unsigned K = k + m;
            pp += K;
            unsigned sub = m ? 0x80000000u : 0u;
            low  = (low << K) ^ sub;
            high = ((high << K) + ((1u << K) - 1u)) ^ sub;
        }
    }
}

// Serial ripple-carry (batched loads), then flush fix-up.
__global__ __launch_bounds__(64) void k_carry2(const unsigned long long* __restrict__ limb,
                                               unsigned* __restrict__ res,
                                               unsigned* __restrict__ hdr) {
    if (threadIdx.x != 0 || blockIdx.x != 0) return;
    unsigned long long c = 0ull;
    const uint4* lp = (const uint4*)limb;
    unsigned first = 0;
    for (int b = 0; b < NLIMB / 16; ++b) {        // 4097 batches of 16 limbs
        uint4 q[8];
#pragma unroll
        for (int u = 0; u < 8; ++u) q[u] = lp[b * 8 + u];
#pragma unroll
        for (int u = 0; u < 8; ++u) {
            unsigned long long l0 = (unsigned long long)q[u].x | ((unsigned long long)q[u].y << 32);
            unsigned long long l1 = (unsigned long long)q[u].z | ((unsigned long long)q[u].w << 32);
            unsigned long long t = l0 + c;
            res[b * 16 + 2 * u] = (unsigned)t; c = t >> 32;
            t = l1 + c;
            res[b * 16 + 2 * u + 1] = (unsigned)t; c = t >> 32;
            if (b == 0 && u == 0) first = res[0];
        }
    }
    unsigned fbit = (first >> 30) & 1u;
    res[0] = 1u << (30u + fbit);                  // M = N - low32 + 2^(30+fbit)
    hdr[0] = hdr[1] + 2u;                         // nbits = p_end + 2
}

// out byte q = (M >> (p_end+24-8q)) & 0xFF; zero beyond nbits; out[2^18]=nbits.
__global__ void k_out2(const unsigned* __restrict__ res,
                       const unsigned* __restrict__ hdr, int* __restrict__ out) {
    int q = blockIdx.x * blockDim.x + threadIdx.x;
    if (q > 262144) return;
    unsigned nbits = hdr[0];
    if (q == 262144) { out[q] = (int)nbits; return; }
    if ((unsigned)(8 * q) >= nbits) { out[q] = 0; return; }
    unsigned pend = nbits - 2u;
    unsigned t = pend + 24u - 8u * (unsigned)q;   // >= 15
    unsigned j = t >> 5, o = t & 31u;
    unsigned long long w = (unsigned long long)res[j] | ((unsigned long long)res[j + 1] << 32);
    out[q] = (int)((w >> o) & 0xFFu);
}

extern "C" void kernel_launch(void* const* d_in, const int* in_sizes, int n_in,
                              void* d_out, int out_size, void* d_ws, size_t ws_size,
                              hipStream_t stream) {
    (void)in_sizes; (void)n_in; (void)out_size; (void)ws_size;
    const float* sym = (const float*)d_in[0];
    int* out = (int*)d_out;
    char* ws = (char*)d_ws;
    unsigned*            hdr   = (unsigned*)(ws);
    unsigned*            histG = (unsigned*)(ws + 266240);
    unsigned*            offsG = (unsigned*)(ws + 790528);
    unsigned short*      keys  = (unsigned short*)(ws + 1314816);
    unsigned short*      fb    = (unsigned short*)(ws + 3411968);
    unsigned long long*  limb  = (unsigned long long*)(ws + 266240);  // over dead histG/offsG
    unsigned*            res   = (unsigned*)(ws + 790656);
    uint4*               bnd   = (uint4*)(ws + 1314816);              // over dead keys

    k_keys<<<N_TOT / 256, 256, 0, stream>>>(sym, keys);
    k_hist<<<N_BLKS, 256, 0, stream>>>(keys, histG);
    k_scan<<<1, 512, 0, stream>>>(histG, offsG);
    k_freq<<<N_BLKS, 64, 0, stream>>>(keys, offsG, fb);
    k_zerol<<<(NLIMB + 255) / 256, 256, 0, stream>>>(limb);   // after k_freq (overlay)
    k_enc3<<<1, 64, 0, stream>>>(fb, bnd, hdr);
    k_chunk<<<16, 256, 0, stream>>>(fb, bnd, hdr, limb);
    k_carry2<<<1, 64, 0, stream>>>(limb, res, hdr);
    k_out2<<<1025, 256, 0, stream>>>(res, hdr, out);
}

// Round 11
// 61171.564 us; speedup vs baseline: 1.9924x; 1.0068x over previous
//
#include <hip/hip_runtime.h>
#include <hip/hip_bf16.h>

// Adaptive binary arithmetic encoder, bit-exact port of the JAX reference.
// Round-11: k_enc4 inner loop in hand-scheduled inline SALU asm (29 instr/sym)
// to discriminate issue-cadence vs dep-latency on the serial chain.
// Pipeline otherwise identical to round 10 (G-sum architecture, validated).
//
// ws layout (bytes):
//   0       : hdr     ([0]=nbits, [1]=p_end)
//   266240  : limb    (u64 * 65552)  over dead histG/offsG      (ends 790656)
//   790656  : res     (u32 * 65552)                              (ends 1052864)
//   1314816 : bnd     (uint4 * 4096) over dead keys              (ends 1380352)
//   3411968 : fb      (u16 * 2^20)  f | bit<<15

#define N_TOT (1 << 20)
#define BLK_ELEMS 4096
#define N_BLKS (N_TOT / BLK_ELEMS)   // 256
#define NLIMB 65552

__global__ void k_keys(const float* __restrict__ sym, unsigned short* __restrict__ keys) {
    int t = blockIdx.x * blockDim.x + threadIdx.x;
    if (t >= N_TOT) return;
    unsigned s = 0;
#pragma unroll
    for (int i = 1; i <= 8; ++i) {
        unsigned b = (t >= i) ? (sym[t - i] > 0.0f ? 1u : 0u) : 0u;
        s |= b << (i - 1);
    }
    unsigned bit = sym[t] > 0.0f ? 1u : 0u;
    keys[t] = (unsigned short)((s << 1) | bit);
}

__global__ void k_hist(const unsigned short* __restrict__ keys, unsigned* __restrict__ histG) {
    __shared__ unsigned h[512];
    for (int i = threadIdx.x; i < 512; i += blockDim.x) h[i] = 0;
    __syncthreads();
    int base = blockIdx.x * BLK_ELEMS;
    for (int i = threadIdx.x; i < BLK_ELEMS; i += blockDim.x)
        atomicAdd(&h[keys[base + i]], 1u);
    __syncthreads();
    for (int i = threadIdx.x; i < 512; i += blockDim.x)
        histG[blockIdx.x * 512 + i] = h[i];
}

__global__ void k_scan(const unsigned* __restrict__ histG, unsigned* __restrict__ offsG) {
    int k = blockIdx.x * blockDim.x + threadIdx.x;
    if (k >= 512) return;
    unsigned run = 0;
    for (int b = 0; b < N_BLKS; ++b) {
        offsG[b * 512 + k] = run;
        run += histG[b * 512 + k];
    }
}

__global__ __launch_bounds__(64) void k_freq(const unsigned short* __restrict__ keys,
                                             const unsigned* __restrict__ offsG,
                                             unsigned short* __restrict__ fb) {
    __shared__ unsigned cnt[512];
    int lane = threadIdx.x;
    for (int i = lane; i < 512; i += 64) cnt[i] = offsG[blockIdx.x * 512 + i];
    __syncthreads();
    int base = blockIdx.x * BLK_ELEMS;
    unsigned long long ltm = (1ull << lane) - 1ull;
    for (int c = 0; c < BLK_ELEMS / 64; ++c) {
        int t = base + c * 64 + lane;
        unsigned key = keys[t];
        unsigned bit = key & 1u;
        unsigned state = key >> 1;
        unsigned long long eq = ~0ull;
#pragma unroll
        for (int b = 0; b < 8; ++b) {
            unsigned long long mb = __ballot((state >> b) & 1u);
            eq &= ((state >> b) & 1u) ? mb : ~mb;
        }
        unsigned long long bb = __ballot(bit);
        unsigned long long same = eq & (bit ? bb : ~bb);
        unsigned long long sib  = eq & (bit ? ~bb : bb);
        unsigned base_same = cnt[key];
        unsigned base_sib  = cnt[key ^ 1u];
        __syncthreads();
        unsigned c_same = base_same + (unsigned)__popcll(same & ltm);
        unsigned c_sib  = base_sib  + (unsigned)__popcll(sib & ltm);
        unsigned long long a0 = 1ull + (unsigned long long)(bit ? c_sib : c_same);
        unsigned long long a1 = 1ull + (unsigned long long)(bit ? c_same : c_sib);
        double p0 = (double)a0 / (double)(a0 + a1);
        double fd = rint(p0 * 4094.0) + 1.0;
        fd = fd < 1.0 ? 1.0 : (fd > 4095.0 ? 4095.0 : fd);
        unsigned f = (unsigned)fd;
        fb[t] = (unsigned short)(f | (bit << 15));
        int hi = 63 - __builtin_clzll(same);
        if (lane == hi) cnt[key] = base_same + (unsigned)__popcll(same);
        __syncthreads();
    }
}

__global__ void k_zerol(unsigned long long* __restrict__ limb) {
    int i = blockIdx.x * 256 + threadIdx.x;
    if (i < NLIMB) limb[i] = 0ull;
}

// One symbol of the coder chain in SALU asm. W = packed val reg (2 symbols),
// FI = bfe imm for f (width 12 at off 0/16), BP = bit position (15/31).
// State: %[lo], %[hi], %[pp]; r = rng-1 lives in s24 (refreshed per batch).
#define SYM(W, FI, BP) \
  "s_bfe_u32 s22, " W ", " FI "\n\t"          /* f               */ \
  "s_mul_i32 s20, s24, s22\n\t"               /* tl = r*f        */ \
  "s_mul_hi_u32 s21, s24, s22\n\t"            /* th              */ \
  "s_add_u32 s20, s20, s22\n\t"               /* + f (64-bit)    */ \
  "s_addc_u32 s21, s21, 0\n\t"                                      \
  "s_lshr_b64 s[20:21], s[20:21], 12\n\t"     /* d = s20         */ \
  "s_add_u32 s26, %[lo], s20\n\t"             /* split           */ \
  "s_add_u32 s27, s26, -1\n\t"                /* split-1         */ \
  "s_bitcmp1_b32 " W ", " BP "\n\t"           /* SCC = bit       */ \
  "s_cselect_b32 %[lo], s26, %[lo]\n\t"       /* bit? split:low  */ \
  "s_cselect_b32 %[hi], %[hi], s27\n\t"       /* bit? high:sp-1  */ \
  "s_xor_b32 s28, %[lo], %[hi]\n\t"           /* u               */ \
  "s_flbit_i32_b32 s29, s28\n\t"              /* k = clz(u)      */ \
  "s_andn2_b32 s30, %[lo], %[hi]\n\t"         /* v = low & ~high */ \
  "s_add_u32 s31, s29, 1\n\t"                                       \
  "s_lshl_b32 s30, s30, s31\n\t"              /* vs = v<<(k+1)   */ \
  "s_and_b32 s34, s30, 0x80000000\n\t"        /* sub             */ \
  "s_not_b32 s32, s30\n\t"                                          \
  "s_flbit_i32_b32 s33, s32\n\t"              /* m = clz(~vs)    */ \
  "s_add_u32 s29, s29, s33\n\t"               /* K = k+m         */ \
  "s_add_u32 %[pp], %[pp], s29\n\t"                                 \
  "s_lshl_b32 %[lo], %[lo], s29\n\t"                                \
  "s_lshl_b32 %[hi], %[hi], s29\n\t"                                \
  "s_lshl_b32 s35, 1, s29\n\t"                                      \
  "s_xor_b32 %[lo], %[lo], s34\n\t"                                 \
  "s_add_u32 s35, s35, -1\n\t"                /* 2^K - 1         */ \
  "s_add_u32 %[hi], %[hi], s35\n\t"                                 \
  "s_xor_b32 %[hi], %[hi], s34\n\t"                                 \
  "s_sub_u32 s24, %[hi], %[lo]\n\t"           /* r for next      */

#define SYM2(W) SYM(W, "0x000C0000", "15") SYM(W, "0x000C0010", "31")

// Serial minimal chain (low, high, pp); inner loop in SALU asm.
__global__ __launch_bounds__(64) void k_enc4(const unsigned short* __restrict__ fb,
                                             uint4* __restrict__ bnd,
                                             unsigned* __restrict__ hdr) {
    if (threadIdx.x != 0 || blockIdx.x != 0) return;
    unsigned low = 0u, high = 0xFFFFFFFFu, pp = 0u;
    const uint4* pq = (const uint4*)fb;
    uint4 A = pq[0], B = pq[1];
    const int NC = N_TOT / 16;
    for (int cc = 0; cc < NC; ++cc) {
        if ((cc & 15) == 0) bnd[cc >> 4] = make_uint4(low, high, pp, 0u);
        unsigned w0 = __builtin_amdgcn_readfirstlane(A.x);
        unsigned w1 = __builtin_amdgcn_readfirstlane(A.y);
        unsigned w2 = __builtin_amdgcn_readfirstlane(A.z);
        unsigned w3 = __builtin_amdgcn_readfirstlane(A.w);
        unsigned w4 = __builtin_amdgcn_readfirstlane(B.x);
        unsigned w5 = __builtin_amdgcn_readfirstlane(B.y);
        unsigned w6 = __builtin_amdgcn_readfirstlane(B.z);
        unsigned w7 = __builtin_amdgcn_readfirstlane(B.w);
        if (cc + 1 < NC) { A = pq[2 * cc + 2]; B = pq[2 * cc + 3]; }  // prefetch
        asm volatile(
            "s_sub_u32 s24, %[hi], %[lo]\n\t"
            SYM2("%[w0]") SYM2("%[w1]") SYM2("%[w2]") SYM2("%[w3]")
            SYM2("%[w4]") SYM2("%[w5]") SYM2("%[w6]") SYM2("%[w7]")
            : [lo]"+s"(low), [hi]"+s"(high), [pp]"+s"(pp)
            : [w0]"s"(w0), [w1]"s"(w1), [w2]"s"(w2), [w3]"s"(w3),
              [w4]"s"(w4), [w5]"s"(w5), [w6]"s"(w6), [w7]"s"(w7)
            : "s20","s21","s22","s23","s24","s25","s26","s27","s28","s29",
              "s30","s31","s32","s33","s34","s35","scc");
    }
    hdr[1] = pp;   // p_end
}

// 4096 parallel chunks: re-run chain from boundary state; accumulate d<<sh.
__global__ __launch_bounds__(256) void k_chunk(const unsigned short* __restrict__ fb,
                                               const uint4* __restrict__ bnd,
                                               const unsigned* __restrict__ hdr,
                                               unsigned long long* __restrict__ limb) {
    int c = blockIdx.x * 256 + threadIdx.x;   // 0..4095
    uint4 s = bnd[c];
    unsigned low = s.x, high = s.y, pp = s.z;
    unsigned pend = hdr[1];
    const unsigned* fw = (const unsigned*)fb;
    int base = c * 256;
    for (int i = 0; i < 256; i += 2) {
        unsigned w = fw[(base + i) >> 1];
#pragma unroll
        for (int h = 0; h < 2; ++h) {
            unsigned val = (w >> (h * 16)) & 0xFFFFu;
            unsigned f = val & 0xFFFu;
            unsigned bitv = val >> 15;
            unsigned r = high - low;
            unsigned long long prod = (unsigned long long)r * f + f;
            unsigned d = (unsigned)(prod >> 12);
            unsigned split = low + d;
            if (bitv) {
                unsigned sh = pend - pp;
                unsigned long long v = (unsigned long long)d << (sh & 31u);
                unsigned j = sh >> 5;
                atomicAdd(&limb[j], v & 0xFFFFFFFFull);
                unsigned long long vh = v >> 32;
                if (vh) atomicAdd(&limb[j + 1], vh);
            }
            high = bitv ? high : (split - 1u);
            low  = bitv ? split : low;
            unsigned D = low ^ high;
            unsigned k = (unsigned)__builtin_clz(D);
            unsigned kp1 = k + 1u;
            unsigned m = (unsigned)__builtin_clz((~(low << kp1)) | (high << kp1));
            unsigned K = k + m;
            pp += K;
            unsigned sub = m ? 0x80000000u : 0u;
            low  = (low << K) ^ sub;
            high = ((high << K) + ((1u << K) - 1u)) ^ sub;
        }
    }
}

// Serial ripple-carry (batched loads), then flush fix-up.
__global__ __launch_bounds__(64) void k_carry2(const unsigned long long* __restrict__ limb,
                                               unsigned* __restrict__ res,
                                               unsigned* __restrict__ hdr) {
    if (threadIdx.x != 0 || blockIdx.x != 0) return;
    unsigned long long c = 0ull;
    const uint4* lp = (const uint4*)limb;
    unsigned first = 0;
    for (int b = 0; b < NLIMB / 16; ++b) {
        uint4 q[8];
#pragma unroll
        for (int u = 0; u < 8; ++u) q[u] = lp[b * 8 + u];
#pragma unroll
        for (int u = 0; u < 8; ++u) {
            unsigned long long l0 = (unsigned long long)q[u].x | ((unsigned long long)q[u].y << 32);
            unsigned long long l1 = (unsigned long long)q[u].z | ((unsigned long long)q[u].w << 32);
            unsigned long long t = l0 + c;
            res[b * 16 + 2 * u] = (unsigned)t; c = t >> 32;
            t = l1 + c;
            res[b * 16 + 2 * u + 1] = (unsigned)t; c = t >> 32;
            if (b == 0 && u == 0) first = res[0];
        }
    }
    unsigned fbit = (first >> 30) & 1u;
    res[0] = 1u << (30u + fbit);                  // M = N - low32 + 2^(30+fbit)
    hdr[0] = hdr[1] + 2u;                         // nbits = p_end + 2
}

// out byte q = (M >> (p_end+24-8q)) & 0xFF; zero beyond nbits; out[2^18]=nbits.
__global__ void k_out2(const unsigned* __restrict__ res,
                       const unsigned* __restrict__ hdr, int* __restrict__ out) {
    int q = blockIdx.x * blockDim.x + threadIdx.x;
    if (q > 262144) return;
    unsigned nbits = hdr[0];
    if (q == 262144) { out[q] = (int)nbits; return; }
    if ((unsigned)(8 * q) >= nbits) { out[q] = 0; return; }
    unsigned pend = nbits - 2u;
    unsigned t = pend + 24u - 8u * (unsigned)q;   // >= 15
    unsigned j = t >> 5, o = t & 31u;
    unsigned long long w = (unsigned long long)res[j] | ((unsigned long long)res[j + 1] << 32);
    out[q] = (int)((w >> o) & 0xFFu);
}

extern "C" void kernel_launch(void* const* d_in, const int* in_sizes, int n_in,
                              void* d_out, int out_size, void* d_ws, size_t ws_size,
                              hipStream_t stream) {
    (void)in_sizes; (void)n_in; (void)out_size; (void)ws_size;
    const float* sym = (const float*)d_in[0];
    int* out = (int*)d_out;
    char* ws = (char*)d_ws;
    unsigned*            hdr   = (unsigned*)(ws);
    unsigned*            histG = (unsigned*)(ws + 266240);
    unsigned*            offsG = (unsigned*)(ws + 790528);
    unsigned short*      keys  = (unsigned short*)(ws + 1314816);
    unsigned short*      fb    = (unsigned short*)(ws + 3411968);
    unsigned long long*  limb  = (unsigned long long*)(ws + 266240);  // over dead histG/offsG
    unsigned*            res   = (unsigned*)(ws + 790656);
    uint4*               bnd   = (uint4*)(ws + 1314816);              // over dead keys

    k_keys<<<N_TOT / 256, 256, 0, stream>>>(sym, keys);
    k_hist<<<N_BLKS, 256, 0, stream>>>(keys, histG);
    k_scan<<<1, 512, 0, stream>>>(histG, offsG);
    k_freq<<<N_BLKS, 64, 0, stream>>>(keys, offsG, fb);
    k_zerol<<<(NLIMB + 255) / 256, 256, 0, stream>>>(limb);   // after k_freq (overlay)
    k_enc4<<<1, 64, 0, stream>>>(fb, bnd, hdr);
    k_chunk<<<16, 256, 0, stream>>>(fb, bnd, hdr, limb);
    k_carry2<<<1, 64, 0, stream>>>(limb, res, hdr);
    k_out2<<<1025, 256, 0, stream>>>(res, hdr, out);
}

// Round 12
// 56805.463 us; speedup vs baseline: 2.1456x; 1.0769x over previous
//
#include <hip/hip_runtime.h>
#include <hip/hip_bf16.h>

// Adaptive binary arithmetic encoder, bit-exact port of the JAX reference.
// Round-12: serial chain trimmed to 27 SALU instrs/symbol (no pp, no literals,
// fused hi-update); pp reconstructed by parallel two-pass chunk re-execution.
//
// ws layout (bytes):
//   0       : hdr     ([0]=nbits, [1]=p_end)
//   266240  : limb    (u64 * 65552)  over dead histG/offsG      (ends 790656)
//   790656  : res     (u32 * 65552)                              (ends 1052864)
//   1314816 : bnd     (uint2 * 4096) over dead keys              (ends 1347584)
//   1347584 : dpp     (u32 * 4096)                               (ends 1363968)
//   1363968 : ppb     (u32 * 4096)                               (ends 1380352)
//   3411968 : fb      (u16 * 2^20)  f | bit<<15

#define N_TOT (1 << 20)
#define BLK_ELEMS 4096
#define N_BLKS (N_TOT / BLK_ELEMS)   // 256
#define NLIMB 65552

__global__ void k_keys(const float* __restrict__ sym, unsigned short* __restrict__ keys) {
    int t = blockIdx.x * blockDim.x + threadIdx.x;
    if (t >= N_TOT) return;
    unsigned s = 0;
#pragma unroll
    for (int i = 1; i <= 8; ++i) {
        unsigned b = (t >= i) ? (sym[t - i] > 0.0f ? 1u : 0u) : 0u;
        s |= b << (i - 1);
    }
    unsigned bit = sym[t] > 0.0f ? 1u : 0u;
    keys[t] = (unsigned short)((s << 1) | bit);
}

__global__ void k_hist(const unsigned short* __restrict__ keys, unsigned* __restrict__ histG) {
    __shared__ unsigned h[512];
    for (int i = threadIdx.x; i < 512; i += blockDim.x) h[i] = 0;
    __syncthreads();
    int base = blockIdx.x * BLK_ELEMS;
    for (int i = threadIdx.x; i < BLK_ELEMS; i += blockDim.x)
        atomicAdd(&h[keys[base + i]], 1u);
    __syncthreads();
    for (int i = threadIdx.x; i < 512; i += blockDim.x)
        histG[blockIdx.x * 512 + i] = h[i];
}

__global__ void k_scan(const unsigned* __restrict__ histG, unsigned* __restrict__ offsG) {
    int k = blockIdx.x * blockDim.x + threadIdx.x;
    if (k >= 512) return;
    unsigned run = 0;
    for (int b = 0; b < N_BLKS; ++b) {
        offsG[b * 512 + k] = run;
        run += histG[b * 512 + k];
    }
}

__global__ __launch_bounds__(64) void k_freq(const unsigned short* __restrict__ keys,
                                             const unsigned* __restrict__ offsG,
                                             unsigned short* __restrict__ fb) {
    __shared__ unsigned cnt[512];
    int lane = threadIdx.x;
    for (int i = lane; i < 512; i += 64) cnt[i] = offsG[blockIdx.x * 512 + i];
    __syncthreads();
    int base = blockIdx.x * BLK_ELEMS;
    unsigned long long ltm = (1ull << lane) - 1ull;
    for (int c = 0; c < BLK_ELEMS / 64; ++c) {
        int t = base + c * 64 + lane;
        unsigned key = keys[t];
        unsigned bit = key & 1u;
        unsigned state = key >> 1;
        unsigned long long eq = ~0ull;
#pragma unroll
        for (int b = 0; b < 8; ++b) {
            unsigned long long mb = __ballot((state >> b) & 1u);
            eq &= ((state >> b) & 1u) ? mb : ~mb;
        }
        unsigned long long bb = __ballot(bit);
        unsigned long long same = eq & (bit ? bb : ~bb);
        unsigned long long sib  = eq & (bit ? ~bb : bb);
        unsigned base_same = cnt[key];
        unsigned base_sib  = cnt[key ^ 1u];
        __syncthreads();
        unsigned c_same = base_same + (unsigned)__popcll(same & ltm);
        unsigned c_sib  = base_sib  + (unsigned)__popcll(sib & ltm);
        unsigned long long a0 = 1ull + (unsigned long long)(bit ? c_sib : c_same);
        unsigned long long a1 = 1ull + (unsigned long long)(bit ? c_same : c_sib);
        double p0 = (double)a0 / (double)(a0 + a1);
        double fd = rint(p0 * 4094.0) + 1.0;
        fd = fd < 1.0 ? 1.0 : (fd > 4095.0 ? 4095.0 : fd);
        unsigned f = (unsigned)fd;
        fb[t] = (unsigned short)(f | (bit << 15));
        int hi = 63 - __builtin_clzll(same);
        if (lane == hi) cnt[key] = base_same + (unsigned)__popcll(same);
        __syncthreads();
    }
}

__global__ void k_zerol(unsigned long long* __restrict__ limb) {
    int i = blockIdx.x * 256 + threadIdx.x;
    if (i < NLIMB) limb[i] = 0ull;
}

// One symbol, 27 SALU instrs, all 4-byte encodings (no literals).
// State: %[lo], %[hi]; r in s24. FI = preloaded bfe imm reg, BP = bit pos imm.
#define SYM(W, FI, BP) \
  "s_bfe_u32 s22, " W ", " FI "\n\t"          /* f                      */ \
  "s_mul_i32 s20, s24, s22\n\t"               /* r*f lo                 */ \
  "s_mul_hi_u32 s21, s24, s22\n\t"            /* r*f hi                 */ \
  "s_add_u32 s20, s20, s22\n\t"               /* + f => rng*f (64b)     */ \
  "s_addc_u32 s21, s21, 0\n\t"                                             \
  "s_lshr_b64 s[20:21], s[20:21], 12\n\t"     /* d                      */ \
  "s_add_u32 s26, %[lo], s20\n\t"             /* split                  */ \
  "s_add_u32 s27, s26, -1\n\t"                /* split-1                */ \
  "s_bitcmp1_b32 " W ", " BP "\n\t"           /* SCC = bit              */ \
  "s_cselect_b32 %[lo], s26, %[lo]\n\t"                                    \
  "s_cselect_b32 %[hi], %[hi], s27\n\t"                                    \
  "s_xor_b32 s28, %[lo], %[hi]\n\t"                                        \
  "s_flbit_i32_b32 s29, s28\n\t"              /* k                      */ \
  "s_andn2_b32 s30, %[lo], %[hi]\n\t"                                      \
  "s_add_u32 s31, s29, 1\n\t"                                              \
  "s_lshl_b32 s30, s30, s31\n\t"              /* vs                     */ \
  "s_and_b32 s34, s30, %[msk]\n\t"            /* sub                    */ \
  "s_not_b32 s32, s30\n\t"                                                 \
  "s_flbit_i32_b32 s33, s32\n\t"              /* m                      */ \
  "s_add_u32 s29, s29, s33\n\t"               /* K                      */ \
  "s_lshl_b32 %[lo], %[lo], s29\n\t"                                       \
  "s_add_u32 %[hi], %[hi], 1\n\t"             /* hi+1 (mod 2^32 ok)     */ \
  "s_lshl_b32 %[hi], %[hi], s29\n\t"                                       \
  "s_xor_b32 %[lo], %[lo], s34\n\t"                                        \
  "s_add_u32 %[hi], %[hi], -1\n\t"            /* (hi+1)<<K - 1          */ \
  "s_xor_b32 %[hi], %[hi], s34\n\t"                                        \
  "s_sub_u32 s24, %[hi], %[lo]\n\t"           /* r for next             */

#define SYM2(W) SYM(W, "%[c0]", "15") SYM(W, "%[c1]", "31")

// Serial minimal chain (low, high); 32 symbols/iteration.
__global__ __launch_bounds__(64) void k_enc5(const unsigned short* __restrict__ fb,
                                             uint2* __restrict__ bnd) {
    if (threadIdx.x != 0 || blockIdx.x != 0) return;
    unsigned low = 0u, high = 0xFFFFFFFFu;
    unsigned c0 = 0x000C0000u, c1 = 0x000C0010u, mk = 0x80000000u;
    const uint4* pq = (const uint4*)fb;
    uint4 A = pq[0], B = pq[1], C = pq[2], D = pq[3];
    const int NC = N_TOT / 32;
    for (int cc = 0; cc < NC; ++cc) {
        if ((cc & 7) == 0) bnd[cc >> 3] = make_uint2(low, high);   // every 256 syms
        unsigned w0 = __builtin_amdgcn_readfirstlane(A.x);
        unsigned w1 = __builtin_amdgcn_readfirstlane(A.y);
        unsigned w2 = __builtin_amdgcn_readfirstlane(A.z);
        unsigned w3 = __builtin_amdgcn_readfirstlane(A.w);
        unsigned w4 = __builtin_amdgcn_readfirstlane(B.x);
        unsigned w5 = __builtin_amdgcn_readfirstlane(B.y);
        unsigned w6 = __builtin_amdgcn_readfirstlane(B.z);
        unsigned w7 = __builtin_amdgcn_readfirstlane(B.w);
        unsigned w8 = __builtin_amdgcn_readfirstlane(C.x);
        unsigned w9 = __builtin_amdgcn_readfirstlane(C.y);
        unsigned wa = __builtin_amdgcn_readfirstlane(C.z);
        unsigned wb = __builtin_amdgcn_readfirstlane(C.w);
        unsigned wc = __builtin_amdgcn_readfirstlane(D.x);
        unsigned wd = __builtin_amdgcn_readfirstlane(D.y);
        unsigned we = __builtin_amdgcn_readfirstlane(D.z);
        unsigned wf = __builtin_amdgcn_readfirstlane(D.w);
        if (cc + 1 < NC) {
            A = pq[4 * cc + 4]; B = pq[4 * cc + 5];
            C = pq[4 * cc + 6]; D = pq[4 * cc + 7];
        }
        asm volatile(
            "s_sub_u32 s24, %[hi], %[lo]\n\t"
            SYM2("%[w0]") SYM2("%[w1]") SYM2("%[w2]") SYM2("%[w3]")
            SYM2("%[w4]") SYM2("%[w5]") SYM2("%[w6]") SYM2("%[w7]")
            SYM2("%[w8]") SYM2("%[w9]") SYM2("%[wa]") SYM2("%[wb]")
            SYM2("%[wc]") SYM2("%[wd]") SYM2("%[we]") SYM2("%[wf]")
            : [lo]"+s"(low), [hi]"+s"(high)
            : [w0]"s"(w0), [w1]"s"(w1), [w2]"s"(w2), [w3]"s"(w3),
              [w4]"s"(w4), [w5]"s"(w5), [w6]"s"(w6), [w7]"s"(w7),
              [w8]"s"(w8), [w9]"s"(w9), [wa]"s"(wa), [wb]"s"(wb),
              [wc]"s"(wc), [wd]"s"(wd), [we]"s"(we), [wf]"s"(wf),
              [c0]"s"(c0), [c1]"s"(c1), [msk]"s"(mk)
            : "s20","s21","s22","s23","s24","s25","s26","s27","s28","s29",
              "s30","s31","s32","s33","s34","s35","scc");
    }
}

// Pass A: re-run chain per chunk, Delta-pp only (no atomics).
__global__ __launch_bounds__(256) void k_chunkA(const unsigned short* __restrict__ fb,
                                                const uint2* __restrict__ bnd,
                                                unsigned* __restrict__ dpp) {
    int c = blockIdx.x * 256 + threadIdx.x;   // 0..4095
    uint2 s = bnd[c];
    unsigned low = s.x, high = s.y, pp = 0;
    const unsigned* fw = (const unsigned*)fb;
    int base = c * 256;
    for (int i = 0; i < 256; i += 2) {
        unsigned w = fw[(base + i) >> 1];
#pragma unroll
        for (int h = 0; h < 2; ++h) {
            unsigned val = (w >> (h * 16)) & 0xFFFFu;
            unsigned f = val & 0xFFFu;
            unsigned bitv = val >> 15;
            unsigned r = high - low;
            unsigned long long prod = (unsigned long long)r * f + f;
            unsigned d = (unsigned)(prod >> 12);
            unsigned split = low + d;
            high = bitv ? high : (split - 1u);
            low  = bitv ? split : low;
            unsigned D = low ^ high;
            unsigned k = (unsigned)__builtin_clz(D);
            unsigned kp1 = k + 1u;
            unsigned m = (unsigned)__builtin_clz((~(low << kp1)) | (high << kp1));
            unsigned K = k + m;
            pp += K;
            unsigned sub = m ? 0x80000000u : 0u;
            low  = (low << K) ^ sub;
            high = ((high << K) + ((1u << K) - 1u)) ^ sub;
        }
    }
    dpp[c] = pp;
}

// Exclusive scan of dpp (4096) -> ppb; total -> hdr[1] = p_end.
__global__ __launch_bounds__(256) void k_scan2(const unsigned* __restrict__ dpp,
                                               unsigned* __restrict__ ppb,
                                               unsigned* __restrict__ hdr) {
    __shared__ unsigned part[256];
    int t = threadIdx.x;
    uint4 v[4];
    const uint4* dp = (const uint4*)(dpp + t * 16);
    unsigned s = 0;
#pragma unroll
    for (int i = 0; i < 4; ++i) { v[i] = dp[i]; s += v[i].x + v[i].y + v[i].z + v[i].w; }
    part[t] = s;
    __syncthreads();
    if (t == 0) {
        unsigned run = 0;
        for (int i = 0; i < 256; ++i) { unsigned x = part[i]; part[i] = run; run += x; }
        hdr[1] = run;
    }
    __syncthreads();
    unsigned run = part[t];
    unsigned* pb = ppb + t * 16;
#pragma unroll
    for (int i = 0; i < 4; ++i) {
        pb[4 * i + 0] = run; run += v[i].x;
        pb[4 * i + 1] = run; run += v[i].y;
        pb[4 * i + 2] = run; run += v[i].z;
        pb[4 * i + 3] = run; run += v[i].w;
    }
}

// Pass B: re-run chain with absolute pp; accumulate d<<sh into limbs.
__global__ __launch_bounds__(256) void k_chunkB(const unsigned short* __restrict__ fb,
                                                const uint2* __restrict__ bnd,
                                                const unsigned* __restrict__ ppb,
                                                const unsigned* __restrict__ hdr,
                                                unsigned long long* __restrict__ limb) {
    int c = blockIdx.x * 256 + threadIdx.x;   // 0..4095
    uint2 s = bnd[c];
    unsigned low = s.x, high = s.y, pp = ppb[c];
    unsigned pend = hdr[1];
    const unsigned* fw = (const unsigned*)fb;
    int base = c * 256;
    for (int i = 0; i < 256; i += 2) {
        unsigned w = fw[(base + i) >> 1];
#pragma unroll
        for (int h = 0; h < 2; ++h) {
            unsigned val = (w >> (h * 16)) & 0xFFFFu;
            unsigned f = val & 0xFFFu;
            unsigned bitv = val >> 15;
            unsigned r = high - low;
            unsigned long long prod = (unsigned long long)r * f + f;
            unsigned d = (unsigned)(prod >> 12);
            unsigned split = low + d;
            if (bitv) {
                unsigned sh = pend - pp;
                unsigned long long v = (unsigned long long)d << (sh & 31u);
                unsigned j = sh >> 5;
                atomicAdd(&limb[j], v & 0xFFFFFFFFull);
                unsigned long long vh = v >> 32;
                if (vh) atomicAdd(&limb[j + 1], vh);
            }
            high = bitv ? high : (split - 1u);
            low  = bitv ? split : low;
            unsigned D = low ^ high;
            unsigned k = (unsigned)__builtin_clz(D);
            unsigned kp1 = k + 1u;
            unsigned m = (unsigned)__builtin_clz((~(low << kp1)) | (high << kp1));
            unsigned K = k + m;
            pp += K;
            unsigned sub = m ? 0x80000000u : 0u;
            low  = (low << K) ^ sub;
            high = ((high << K) + ((1u << K) - 1u)) ^ sub;
        }
    }
}

// Serial ripple-carry (batched loads), then flush fix-up.
__global__ __launch_bounds__(64) void k_carry2(const unsigned long long* __restrict__ limb,
                                               unsigned* __restrict__ res,
                                               unsigned* __restrict__ hdr) {
    if (threadIdx.x != 0 || blockIdx.x != 0) return;
    unsigned long long c = 0ull;
    const uint4* lp = (const uint4*)limb;
    unsigned first = 0;
    for (int b = 0; b < NLIMB / 16; ++b) {
        uint4 q[8];
#pragma unroll
        for (int u = 0; u < 8; ++u) q[u] = lp[b * 8 + u];
#pragma unroll
        for (int u = 0; u < 8; ++u) {
            unsigned long long l0 = (unsigned long long)q[u].x | ((unsigned long long)q[u].y << 32);
            unsigned long long l1 = (unsigned long long)q[u].z | ((unsigned long long)q[u].w << 32);
            unsigned long long t = l0 + c;
            res[b * 16 + 2 * u] = (unsigned)t; c = t >> 32;
            t = l1 + c;
            res[b * 16 + 2 * u + 1] = (unsigned)t; c = t >> 32;
            if (b == 0 && u == 0) first = res[0];
        }
    }
    unsigned fbit = (first >> 30) & 1u;
    res[0] = 1u << (30u + fbit);                  // M = N - low32 + 2^(30+fbit)
    hdr[0] = hdr[1] + 2u;                         // nbits = p_end + 2
}

// out byte q = (M >> (p_end+24-8q)) & 0xFF; zero beyond nbits; out[2^18]=nbits.
__global__ void k_out2(const unsigned* __restrict__ res,
                       const unsigned* __restrict__ hdr, int* __restrict__ out) {
    int q = blockIdx.x * blockDim.x + threadIdx.x;
    if (q > 262144) return;
    unsigned nbits = hdr[0];
    if (q == 262144) { out[q] = (int)nbits; return; }
    if ((unsigned)(8 * q) >= nbits) { out[q] = 0; return; }
    unsigned pend = nbits - 2u;
    unsigned t = pend + 24u - 8u * (unsigned)q;   // >= 15
    unsigned j = t >> 5, o = t & 31u;
    unsigned long long w = (unsigned long long)res[j] | ((unsigned long long)res[j + 1] << 32);
    out[q] = (int)((w >> o) & 0xFFu);
}

extern "C" void kernel_launch(void* const* d_in, const int* in_sizes, int n_in,
                              void* d_out, int out_size, void* d_ws, size_t ws_size,
                              hipStream_t stream) {
    (void)in_sizes; (void)n_in; (void)out_size; (void)ws_size;
    const float* sym = (const float*)d_in[0];
    int* out = (int*)d_out;
    char* ws = (char*)d_ws;
    unsigned*            hdr   = (unsigned*)(ws);
    unsigned*            histG = (unsigned*)(ws + 266240);
    unsigned*            offsG = (unsigned*)(ws + 790528);
    unsigned short*      keys  = (unsigned short*)(ws + 1314816);
    unsigned short*      fb    = (unsigned short*)(ws + 3411968);
    unsigned long long*  limb  = (unsigned long long*)(ws + 266240);  // over dead histG/offsG
    unsigned*            res   = (unsigned*)(ws + 790656);
    uint2*               bnd   = (uint2*)(ws + 1314816);              // over dead keys
    unsigned*            dpp   = (unsigned*)(ws + 1347584);
    unsigned*            ppb   = (unsigned*)(ws + 1363968);

    k_keys<<<N_TOT / 256, 256, 0, stream>>>(sym, keys);
    k_hist<<<N_BLKS, 256, 0, stream>>>(keys, histG);
    k_scan<<<1, 512, 0, stream>>>(histG, offsG);
    k_freq<<<N_BLKS, 64, 0, stream>>>(keys, offsG, fb);
    k_zerol<<<(NLIMB + 255) / 256, 256, 0, stream>>>(limb);   // after k_freq (overlay)
    k_enc5<<<1, 64, 0, stream>>>(fb, bnd);
    k_chunkA<<<16, 256, 0, stream>>>(fb, bnd, dpp);
    k_scan2<<<1, 256, 0, stream>>>(dpp, ppb, hdr);
    k_chunkB<<<16, 256, 0, stream>>>(fb, bnd, ppb, hdr, limb);
    k_carry2<<<1, 64, 0, stream>>>(limb, res, hdr);
    k_out2<<<1025, 256, 0, stream>>>(res, hdr, out);
}

// Round 13
// 50508.292 us; speedup vs baseline: 2.4131x; 1.1247x over previous
//
#include <hip/hip_runtime.h>
#include <hip/hip_bf16.h>

// Adaptive binary arithmetic encoder, bit-exact port of the JAX reference.
// Round-13: serial body compressed to 23/24 SALU instrs via
//  (a) f2 = f<<20 preformat -> d = mulhi(rng, f2) exactly (rng=0 => d=f2 via SCC),
//  (b) complement state (lo, nh=~hi): nh' = (nh<<K)^sub (2-instr hi-renorm),
//  (c) vs = (v<<1)<<k.
// fb format: u16 = (f<<4) | bit.  bnd stores (lo, nh).
//
// ws layout (bytes):
//   0       : hdr     ([0]=nbits, [1]=p_end)
//   266240  : limb    (u64 * 65552)  over dead histG/offsG      (ends 790656)
//   790656  : res     (u32 * 65552)                              (ends 1052864)
//   1314816 : bnd     (uint2 * 4096) over dead keys              (ends 1347584)
//   1347584 : dpp     (u32 * 4096)                               (ends 1363968)
//   1363968 : ppb     (u32 * 4096)                               (ends 1380352)
//   3411968 : fb      (u16 * 2^20)  (f<<4) | bit

#define N_TOT (1 << 20)
#define BLK_ELEMS 4096
#define N_BLKS (N_TOT / BLK_ELEMS)   // 256
#define NLIMB 65552

__global__ void k_keys(const float* __restrict__ sym, unsigned short* __restrict__ keys) {
    int t = blockIdx.x * blockDim.x + threadIdx.x;
    if (t >= N_TOT) return;
    unsigned s = 0;
#pragma unroll
    for (int i = 1; i <= 8; ++i) {
        unsigned b = (t >= i) ? (sym[t - i] > 0.0f ? 1u : 0u) : 0u;
        s |= b << (i - 1);
    }
    unsigned bit = sym[t] > 0.0f ? 1u : 0u;
    keys[t] = (unsigned short)((s << 1) | bit);
}

__global__ void k_hist(const unsigned short* __restrict__ keys, unsigned* __restrict__ histG) {
    __shared__ unsigned h[512];
    for (int i = threadIdx.x; i < 512; i += blockDim.x) h[i] = 0;
    __syncthreads();
    int base = blockIdx.x * BLK_ELEMS;
    for (int i = threadIdx.x; i < BLK_ELEMS; i += blockDim.x)
        atomicAdd(&h[keys[base + i]], 1u);
    __syncthreads();
    for (int i = threadIdx.x; i < 512; i += blockDim.x)
        histG[blockIdx.x * 512 + i] = h[i];
}

__global__ void k_scan(const unsigned* __restrict__ histG, unsigned* __restrict__ offsG) {
    int k = blockIdx.x * blockDim.x + threadIdx.x;
    if (k >= 512) return;
    unsigned run = 0;
    for (int b = 0; b < N_BLKS; ++b) {
        offsG[b * 512 + k] = run;
        run += histG[b * 512 + k];
    }
}

__global__ __launch_bounds__(64) void k_freq(const unsigned short* __restrict__ keys,
                                             const unsigned* __restrict__ offsG,
                                             unsigned short* __restrict__ fb) {
    __shared__ unsigned cnt[512];
    int lane = threadIdx.x;
    for (int i = lane; i < 512; i += 64) cnt[i] = offsG[blockIdx.x * 512 + i];
    __syncthreads();
    int base = blockIdx.x * BLK_ELEMS;
    unsigned long long ltm = (1ull << lane) - 1ull;
    for (int c = 0; c < BLK_ELEMS / 64; ++c) {
        int t = base + c * 64 + lane;
        unsigned key = keys[t];
        unsigned bit = key & 1u;
        unsigned state = key >> 1;
        unsigned long long eq = ~0ull;
#pragma unroll
        for (int b = 0; b < 8; ++b) {
            unsigned long long mb = __ballot((state >> b) & 1u);
            eq &= ((state >> b) & 1u) ? mb : ~mb;
        }
        unsigned long long bb = __ballot(bit);
        unsigned long long same = eq & (bit ? bb : ~bb);
        unsigned long long sib  = eq & (bit ? ~bb : bb);
        unsigned base_same = cnt[key];
        unsigned base_sib  = cnt[key ^ 1u];
        __syncthreads();
        unsigned c_same = base_same + (unsigned)__popcll(same & ltm);
        unsigned c_sib  = base_sib  + (unsigned)__popcll(sib & ltm);
        unsigned long long a0 = 1ull + (unsigned long long)(bit ? c_sib : c_same);
        unsigned long long a1 = 1ull + (unsigned long long)(bit ? c_same : c_sib);
        double p0 = (double)a0 / (double)(a0 + a1);
        double fd = rint(p0 * 4094.0) + 1.0;
        fd = fd < 1.0 ? 1.0 : (fd > 4095.0 ? 4095.0 : fd);
        unsigned f = (unsigned)fd;
        fb[t] = (unsigned short)((f << 4) | bit);
        int hi = 63 - __builtin_clzll(same);
        if (lane == hi) cnt[key] = base_same + (unsigned)__popcll(same);
        __syncthreads();
    }
}

__global__ void k_zerol(unsigned long long* __restrict__ limb) {
    int i = blockIdx.x * 256 + threadIdx.x;
    if (i < NLIMB) limb[i] = 0ull;
}

// Core (after f2 in s22): t, rng(SCC), dh, d, split, nsp, <bitcmp>, csels, renorm.
#define SYM_CORE1 \
  "s_add_u32 s23, %[lo], %[nh]\n\t"          /* t = lo+nh               */ \
  "s_sub_u32 s24, 0, s23\n\t"                /* rng = -t; SCC = t!=0    */ \
  "s_mul_hi_u32 s21, s24, s22\n\t"           /* dh = mulhi(rng, f2)     */ \
  "s_cselect_b32 s20, s21, s22\n\t"          /* d  = SCC ? dh : f2      */ \
  "s_add_u32 s26, %[lo], s20\n\t"            /* split                   */ \
  "s_sub_u32 s27, 0, s26\n\t"                /* nsp = -split = ~(sp-1)  */
#define SYM_CORE2 \
  "s_cselect_b32 %[lo], s26, %[lo]\n\t"      /* bit ? split : lo        */ \
  "s_cselect_b32 %[nh], %[nh], s27\n\t"      /* bit ? nh   : nsp        */ \
  "s_xnor_b32 s28, %[lo], %[nh]\n\t"         /* u = lo^hi               */ \
  "s_flbit_i32_b32 s29, s28\n\t"             /* k                       */ \
  "s_and_b32 s30, %[lo], %[nh]\n\t"          /* v = lo & ~hi            */ \
  "s_lshl_b32 s30, s30, 1\n\t"                                             \
  "s_lshl_b32 s30, s30, s29\n\t"             /* vs = v<<(k+1)           */ \
  "s_and_b32 s34, s30, %[mk]\n\t"            /* sub                     */ \
  "s_not_b32 s32, s30\n\t"                                                 \
  "s_flbit_i32_b32 s33, s32\n\t"             /* m                       */ \
  "s_add_u32 s29, s29, s33\n\t"              /* K = k+m                 */ \
  "s_lshl_b32 %[lo], %[lo], s29\n\t"                                       \
  "s_xor_b32 %[lo], %[lo], s34\n\t"                                        \
  "s_lshl_b32 %[nh], %[nh], s29\n\t"                                       \
  "s_xor_b32 %[nh], %[nh], s34\n\t"          /* nh' = (nh<<K)^sub       */

#define SYMA(W) /* low half: f2 = (w<<16)&mF, bit = w.0  -> 24 instrs */ \
  "s_lshl_b32 s25, " W ", 16\n\t"                                          \
  "s_and_b32 s22, s25, %[mF]\n\t"                                          \
  SYM_CORE1                                                                \
  "s_bitcmp1_b32 " W ", 0\n\t"                                             \
  SYM_CORE2
#define SYMB(W) /* high half: f2 = w&mF, bit = w.16     -> 23 instrs */ \
  "s_and_b32 s22, " W ", %[mF]\n\t"                                        \
  SYM_CORE1                                                                \
  "s_bitcmp1_b32 " W ", 16\n\t"                                            \
  SYM_CORE2
#define SYM2(W) SYMA(W) SYMB(W)

// Serial minimal chain (lo, nh=~hi); 32 symbols/iteration.
__global__ __launch_bounds__(64) void k_enc6(const unsigned short* __restrict__ fb,
                                             uint2* __restrict__ bnd) {
    if (threadIdx.x != 0 || blockIdx.x != 0) return;
    unsigned low = 0u, nh = 0u;                 // lo=0, hi=0xFFFFFFFF -> nh=0
    unsigned mF = 0xFFF00000u, mk = 0x80000000u;
    const uint4* pq = (const uint4*)fb;
    uint4 A = pq[0], B = pq[1], C = pq[2], D = pq[3];
    const int NC = N_TOT / 32;
    for (int cc = 0; cc < NC; ++cc) {
        if ((cc & 7) == 0) bnd[cc >> 3] = make_uint2(low, nh);   // every 256 syms
        unsigned w0 = __builtin_amdgcn_readfirstlane(A.x);
        unsigned w1 = __builtin_amdgcn_readfirstlane(A.y);
        unsigned w2 = __builtin_amdgcn_readfirstlane(A.z);
        unsigned w3 = __builtin_amdgcn_readfirstlane(A.w);
        unsigned w4 = __builtin_amdgcn_readfirstlane(B.x);
        unsigned w5 = __builtin_amdgcn_readfirstlane(B.y);
        unsigned w6 = __builtin_amdgcn_readfirstlane(B.z);
        unsigned w7 = __builtin_amdgcn_readfirstlane(B.w);
        unsigned w8 = __builtin_amdgcn_readfirstlane(C.x);
        unsigned w9 = __builtin_amdgcn_readfirstlane(C.y);
        unsigned wa = __builtin_amdgcn_readfirstlane(C.z);
        unsigned wb = __builtin_amdgcn_readfirstlane(C.w);
        unsigned wc = __builtin_amdgcn_readfirstlane(D.x);
        unsigned wd = __builtin_amdgcn_readfirstlane(D.y);
        unsigned we = __builtin_amdgcn_readfirstlane(D.z);
        unsigned wf = __builtin_amdgcn_readfirstlane(D.w);
        if (cc + 1 < NC) {
            A = pq[4 * cc + 4]; B = pq[4 * cc + 5];
            C = pq[4 * cc + 6]; D = pq[4 * cc + 7];
        }
        asm volatile(
            SYM2("%[w0]") SYM2("%[w1]") SYM2("%[w2]") SYM2("%[w3]")
            SYM2("%[w4]") SYM2("%[w5]") SYM2("%[w6]") SYM2("%[w7]")
            SYM2("%[w8]") SYM2("%[w9]") SYM2("%[wa]") SYM2("%[wb]")
            SYM2("%[wc]") SYM2("%[wd]") SYM2("%[we]") SYM2("%[wf]")
            : [lo]"+s"(low), [nh]"+s"(nh)
            : [w0]"s"(w0), [w1]"s"(w1), [w2]"s"(w2), [w3]"s"(w3),
              [w4]"s"(w4), [w5]"s"(w5), [w6]"s"(w6), [w7]"s"(w7),
              [w8]"s"(w8), [w9]"s"(w9), [wa]"s"(wa), [wb]"s"(wb),
              [wc]"s"(wc), [wd]"s"(wd), [we]"s"(we), [wf]"s"(wf),
              [mF]"s"(mF), [mk]"s"(mk)
            : "s20","s21","s22","s23","s24","s25","s26","s27","s28","s29",
              "s30","s31","s32","s33","s34","s35","scc");
    }
}

// Pass A: re-run chain per chunk, Delta-pp only (no atomics).
__global__ __launch_bounds__(256) void k_chunkA(const unsigned short* __restrict__ fb,
                                                const uint2* __restrict__ bnd,
                                                unsigned* __restrict__ dpp) {
    int c = blockIdx.x * 256 + threadIdx.x;   // 0..4095
    uint2 s = bnd[c];
    unsigned low = s.x, high = ~s.y, pp = 0;  // bnd stores (lo, ~hi)
    const unsigned* fw = (const unsigned*)fb;
    int base = c * 256;
    for (int i = 0; i < 256; i += 2) {
        unsigned w = fw[(base + i) >> 1];
#pragma unroll
        for (int h = 0; h < 2; ++h) {
            unsigned val = (w >> (h * 16)) & 0xFFFFu;
            unsigned f = val >> 4;
            unsigned bitv = val & 1u;
            unsigned r = high - low;
            unsigned long long prod = (unsigned long long)r * f + f;
            unsigned d = (unsigned)(prod >> 12);
            unsigned split = low + d;
            high = bitv ? high : (split - 1u);
            low  = bitv ? split : low;
            unsigned D = low ^ high;
            unsigned k = (unsigned)__builtin_clz(D);
            unsigned kp1 = k + 1u;
            unsigned m = (unsigned)__builtin_clz((~(low << kp1)) | (high << kp1));
            unsigned K = k + m;
            pp += K;
            unsigned sub = m ? 0x80000000u : 0u;
            low  = (low << K) ^ sub;
            high = ((high << K) + ((1u << K) - 1u)) ^ sub;
        }
    }
    dpp[c] = pp;
}

// Exclusive scan of dpp (4096) -> ppb; total -> hdr[1] = p_end.
__global__ __launch_bounds__(256) void k_scan2(const unsigned* __restrict__ dpp,
                                               unsigned* __restrict__ ppb,
                                               unsigned* __restrict__ hdr) {
    __shared__ unsigned part[256];
    int t = threadIdx.x;
    uint4 v[4];
    const uint4* dp = (const uint4*)(dpp + t * 16);
    unsigned s = 0;
#pragma unroll
    for (int i = 0; i < 4; ++i) { v[i] = dp[i]; s += v[i].x + v[i].y + v[i].z + v[i].w; }
    part[t] = s;
    __syncthreads();
    if (t == 0) {
        unsigned run = 0;
        for (int i = 0; i < 256; ++i) { unsigned x = part[i]; part[i] = run; run += x; }
        hdr[1] = run;
    }
    __syncthreads();
    unsigned run = part[t];
    unsigned* pb = ppb + t * 16;
#pragma unroll
    for (int i = 0; i < 4; ++i) {
        pb[4 * i + 0] = run; run += v[i].x;
        pb[4 * i + 1] = run; run += v[i].y;
        pb[4 * i + 2] = run; run += v[i].z;
        pb[4 * i + 3] = run; run += v[i].w;
    }
}

// Pass B: re-run chain with absolute pp; accumulate d<<sh into limbs.
__global__ __launch_bounds__(256) void k_chunkB(const unsigned short* __restrict__ fb,
                                                const uint2* __restrict__ bnd,
                                                const unsigned* __restrict__ ppb,
                                                const unsigned* __restrict__ hdr,
                                                unsigned long long* __restrict__ limb) {
    int c = blockIdx.x * 256 + threadIdx.x;   // 0..4095
    uint2 s = bnd[c];
    unsigned low = s.x, high = ~s.y, pp = ppb[c];   // bnd stores (lo, ~hi)
    unsigned pend = hdr[1];
    const unsigned* fw = (const unsigned*)fb;
    int base = c * 256;
    for (int i = 0; i < 256; i += 2) {
        unsigned w = fw[(base + i) >> 1];
#pragma unroll
        for (int h = 0; h < 2; ++h) {
            unsigned val = (w >> (h * 16)) & 0xFFFFu;
            unsigned f = val >> 4;
            unsigned bitv = val & 1u;
            unsigned r = high - low;
            unsigned long long prod = (unsigned long long)r * f + f;
            unsigned d = (unsigned)(prod >> 12);
            unsigned split = low + d;
            if (bitv) {
                unsigned sh = pend - pp;
                unsigned long long v = (unsigned long long)d << (sh & 31u);
                unsigned j = sh >> 5;
                atomicAdd(&limb[j], v & 0xFFFFFFFFull);
                unsigned long long vh = v >> 32;
                if (vh) atomicAdd(&limb[j + 1], vh);
            }
            high = bitv ? high : (split - 1u);
            low  = bitv ? split : low;
            unsigned D = low ^ high;
            unsigned k = (unsigned)__builtin_clz(D);
            unsigned kp1 = k + 1u;
            unsigned m = (unsigned)__builtin_clz((~(low << kp1)) | (high << kp1));
            unsigned K = k + m;
            pp += K;
            unsigned sub = m ? 0x80000000u : 0u;
            low  = (low << K) ^ sub;
            high = ((high << K) + ((1u << K) - 1u)) ^ sub;
        }
    }
}

// Serial ripple-carry (batched loads), then flush fix-up.
__global__ __launch_bounds__(64) void k_carry2(const unsigned long long* __restrict__ limb,
                                               unsigned* __restrict__ res,
                                               unsigned* __restrict__ hdr) {
    if (threadIdx.x != 0 || blockIdx.x != 0) return;
    unsigned long long c = 0ull;
    const uint4* lp = (const uint4*)limb;
    unsigned first = 0;
    for (int b = 0; b < NLIMB / 16; ++b) {
        uint4 q[8];
#pragma unroll
        for (int u = 0; u < 8; ++u) q[u] = lp[b * 8 + u];
#pragma unroll
        for (int u = 0; u < 8; ++u) {
            unsigned long long l0 = (unsigned long long)q[u].x | ((unsigned long long)q[u].y << 32);
            unsigned long long l1 = (unsigned long long)q[u].z | ((unsigned long long)q[u].w << 32);
            unsigned long long t = l0 + c;
            res[b * 16 + 2 * u] = (unsigned)t; c = t >> 32;
            t = l1 + c;
            res[b * 16 + 2 * u + 1] = (unsigned)t; c = t >> 32;
            if (b == 0 && u == 0) first = res[0];
        }
    }
    unsigned fbit = (first >> 30) & 1u;
    res[0] = 1u << (30u + fbit);                  // M = N - low32 + 2^(30+fbit)
    hdr[0] = hdr[1] + 2u;                         // nbits = p_end + 2
}

// out byte q = (M >> (p_end+24-8q)) & 0xFF; zero beyond nbits; out[2^18]=nbits.
__global__ void k_out2(const unsigned* __restrict__ res,
                       const unsigned* __restrict__ hdr, int* __restrict__ out) {
    int q = blockIdx.x * blockDim.x + threadIdx.x;
    if (q > 262144) return;
    unsigned nbits = hdr[0];
    if (q == 262144) { out[q] = (int)nbits; return; }
    if ((unsigned)(8 * q) >= nbits) { out[q] = 0; return; }
    unsigned pend = nbits - 2u;
    unsigned t = pend + 24u - 8u * (unsigned)q;   // >= 15
    unsigned j = t >> 5, o = t & 31u;
    unsigned long long w = (unsigned long long)res[j] | ((unsigned long long)res[j + 1] << 32);
    out[q] = (int)((w >> o) & 0xFFu);
}

extern "C" void kernel_launch(void* const* d_in, const int* in_sizes, int n_in,
                              void* d_out, int out_size, void* d_ws, size_t ws_size,
                              hipStream_t stream) {
    (void)in_sizes; (void)n_in; (void)out_size; (void)ws_size;
    const float* sym = (const float*)d_in[0];
    int* out = (int*)d_out;
    char* ws = (char*)d_ws;
    unsigned*            hdr   = (unsigned*)(ws);
    unsigned*            histG = (unsigned*)(ws + 266240);
    unsigned*            offsG = (unsigned*)(ws + 790528);
    unsigned short*      keys  = (unsigned short*)(ws + 1314816);
    unsigned short*      fb    = (unsigned short*)(ws + 3411968);
    unsigned long long*  limb  = (unsigned long long*)(ws + 266240);  // over dead histG/offsG
    unsigned*            res   = (unsigned*)(ws + 790656);
    uint2*               bnd   = (uint2*)(ws + 1314816);              // over dead keys
    unsigned*            dpp   = (unsigned*)(ws + 1347584);
    unsigned*            ppb   = (unsigned*)(ws + 1363968);

    k_keys<<<N_TOT / 256, 256, 0, stream>>>(sym, keys);
    k_hist<<<N_BLKS, 256, 0, stream>>>(keys, histG);
    k_scan<<<1, 512, 0, stream>>>(histG, offsG);
    k_freq<<<N_BLKS, 64, 0, stream>>>(keys, offsG, fb);
    k_zerol<<<(NLIMB + 255) / 256, 256, 0, stream>>>(limb);   // after k_freq (overlay)
    k_enc6<<<1, 64, 0, stream>>>(fb, bnd);
    k_chunkA<<<16, 256, 0, stream>>>(fb, bnd, dpp);
    k_scan2<<<1, 256, 0, stream>>>(dpp, ppb, hdr);
    k_chunkB<<<16, 256, 0, stream>>>(fb, bnd, ppb, hdr, limb);
    k_carry2<<<1, 64, 0, stream>>>(limb, res, hdr);
    k_out2<<<1025, 256, 0, stream>>>(res, hdr, out);
}